// Round 6
// baseline (15.682 us; speedup 1.0000x reference)
//
#include <hip/hip_runtime.h>
#include <math.h>

#define NP 4096
#define JC 64            // j-chunk per scan block
#define NIB 16           // collector blocks (16 * 256 = 4096 particles)
#define NSCAN 544        // sum_{ib=0}^{15} 4*(ib+1)  (lower-triangle blocks)
#define NBLK_TOT (NSCAN + NIB)
#define PI_F 3.1415927410125732f

// thresholds (squared, monotone-equivalent to reference's abs() compares)
#define RR2_THR   (8e-06f * 8e-06f)                       // RR^2
#define RO2_THR   (2.815e-05f * 2.815e-05f)               // (RO+RC)^2
#define COLL2_THR (6.3e-06f * 6.3e-06f)                   // (2*RC)^2
#define OVC       (2.1f * 3.15e-06f)                      // 2.1*RC
#define EPS_F     1e-14f

#define C_TV   ((float)(0.2 * 5e-07))         // DT*VEL
#define C_ROT  ((float)(0.2 * 25.0 * 0.0028)) // DT*GAMMA*DR

// Tag protocol: scan block b publishes tags[b] = TAG_BASE | hit (hit in {0,1}).
// ws data is a pure function of the inputs, so a stale tag from a previous
// replay equals the fresh one — the spin only gates the first post-poison
// replay. Dirty path recomputes from d_in only (no partials communicated).
#define TAG_BASE 0x5A5AA5A4u

// ws layout: tags[NSCAN] (uint), then float2 move[NP] (dirty-path scratch)
#define W_MV_OFF 1024    // float offset

__device__ __forceinline__ float angle_diff(float a, float b) {
    float diff = a - b;
    if (diff <= -PI_F) {
        float m = fmodf(diff, PI_F);     // python-mod semantics (divisor > 0)
        if (m < 0.f) m += PI_F;
        diff = m;
    }
    if (diff >= PI_F) diff -= 2.f * PI_F;
    return diff;
}

// epilogue planes 1..4 (new_ori, osum, left, right); caller writes plane 0.
// osx/osy must already include the ro-diagonal contribution.
__device__ __forceinline__ void epilogue4(
    float2 p, float2 o, float dlt, float rnoi,
    float osx, float osy, float nr, float rrx, float rry,
    float sumx, float sumy, int i, float* __restrict__ out)
{
    float ang = atan2f(o.y, o.x);

    float invn = 1.f / fmaxf(nr, 1.f);
    float sgn  = (nr > 0.f) ? 1.f : 0.f;
    float Sx = rrx * invn - p.x * sgn;
    float Sy = rry * invn - p.y * sgn;
    float ddx = -Sx, ddy = -Sy;

    float cmx = sumx * (1.f / 4096.f);
    float cmy = sumy * (1.f / 4096.f);
    float Px = cmx - p.x;
    float Py = cmy - p.y;

    float cd = cosf(dlt), sd = sinf(dlt);
    float lx = Px * cd - Py * sd, ly = Px * sd + Py * cd;   // Ps * e^{+i d}
    float rx = Px * cd + Py * sd, ry = Py * cd - Px * sd;   // Ps * e^{-i d}

    float la = sqrtf(lx * lx + ly * ly);
    float ra = sqrtf(rx * rx + ry * ry);
    float oa = sqrtf(osx * osx + osy * osy);
    float csl = (lx * osx + ly * osy) / (fmaxf(la, EPS_F) * fmaxf(oa, EPS_F));
    float csr = (rx * osx + ry * osy) / (fmaxf(ra, EPS_F) * fmaxf(oa, EPS_F));
    bool lc = (csl >= csr);
    float bx = lc ? lx : rx;
    float by = lc ? ly : ry;

    bool dnz = (ddx != 0.f) || (ddy != 0.f);
    float att;
    if (dnz) {
        att = angle_diff(atan2f(ddy, ddx), ang);
    } else {
        bool bnz = (bx != 0.f) || (by != 0.f);
        float ab = bnz ? atan2f(by, bx) : 0.f;   // angle(1) = 0
        att = angle_diff(ab, ang);
    }

    float s1r = sqrtf(2.0f * 0.0028f);   // sqrt(2*DR)
    float sdt = sqrtf(0.2f);             // sqrt(DT)
    float theta = C_ROT * sinf(att) + rnoi * s1r * sdt;
    float ct = cosf(theta), st = sinf(theta);
    float nox = o.x * ct - o.y * st;
    float noy = o.x * st + o.y * ct;

    out[2 * NP + 2 * i] = nox;  out[2 * NP + 2 * i + 1] = noy;
    out[4 * NP + 2 * i] = osx;  out[4 * NP + 2 * i + 1] = osy;
    out[6 * NP + 2 * i] = lx;   out[6 * NP + 2 * i + 1] = ly;
    out[8 * NP + 2 * i] = rx;   out[8 * NP + 2 * i + 1] = ry;
}

__global__ __launch_bounds__(256, 4) void fused(
    const float* __restrict__ pos, const float* __restrict__ ori,
    const float* __restrict__ del, const float* __restrict__ rno,
    const float* __restrict__ tno, float* __restrict__ out,
    float* __restrict__ ws)
{
    __shared__ float2 s_pos[JC];      // scan stage
    __shared__ float2 s_red[256];     // collector pos-sum
    __shared__ float2 s_p[NP];        // 32 KB, dirty path only
    __shared__ int s_hit;

    unsigned* tags = (unsigned*)ws;
    float2* wmv = (float2*)(ws + W_MV_OFF);

    const int tid = threadIdx.x;
    const int b   = blockIdx.x;
    const float ktr = sqrtf(2.0f * 1.4e-14f) * sqrtf(0.2f);  // sqrt(2*DTRANS)*sqrt(DT)

    if (b < NSCAN) {
        // ============ scan role: lower-triangle proximity DETECTOR ============
        // Any pair relevant to osum/rr (d<=2.815e-5) or collisions (translated
        // d<=6.3e-6 => orig d<=8.6e-6) satisfies d_orig <= RO2 gate; distance
        // is symmetric, so scanning j<i detects every relevant unordered pair.
        int ib = 0;                              // base(ib) = 2*ib*(ib+1)
        while (2 * (ib + 1) * (ib + 2) <= b) ++ib;
        const int js = b - 2 * ib * (ib + 1);    // 0 .. 4*(ib+1)-1
        const int i  = ib * 256 + tid;
        const int jbase = js * JC;

        if (tid == 0) s_hit = 0;
        if (tid < JC) s_pos[tid] = ((const float2*)pos)[jbase + tid];
        __syncthreads();

        float2 pi = ((const float2*)pos)[i];
        bool hit = false;
        #pragma unroll 4
        for (int jj = 0; jj < JC; ++jj) {
            float2 pj = s_pos[jj];
            float dx = pj.x - pi.x;
            float dy = pj.y - pi.y;
            float d2 = dx * dx + dy * dy;
            hit |= (d2 <= RO2_THR) && (jbase + jj < i);   // strict lower triangle
        }
        if (hit) atomicOr(&s_hit, 1);
        __syncthreads();
        if (tid == 0)
            __hip_atomic_store(&tags[b], TAG_BASE | (unsigned)s_hit,
                               __ATOMIC_RELEASE, __HIP_MEMORY_SCOPE_AGENT);
        return;
    }

    // ============ collector role ============
    const int cb = b - NSCAN;        // 0..15
    const int i  = cb * 256 + tid;

    // global position sum for cms (n_a == 4096 exactly; deterministic tree)
    float sx = 0.f, sy = 0.f;
    for (int k = tid; k < NP; k += 256) {
        float2 p = ((const float2*)pos)[k];
        sx += p.x; sy += p.y;
    }
    s_red[tid] = make_float2(sx, sy);
    __syncthreads();
    for (int s = 128; s > 0; s >>= 1) {
        if (tid < s) { s_red[tid].x += s_red[tid + s].x; s_red[tid].y += s_red[tid + s].y; }
        __syncthreads();
    }
    const float sumx = s_red[0].x, sumy = s_red[0].y;

    // spin until all scan tags published (stale==fresh across replays)
    int dirty = 0;
    for (int t = tid; t < NSCAN; t += 256) {
        unsigned v;
        for (;;) {
            v = __hip_atomic_load(&tags[t], __ATOMIC_ACQUIRE, __HIP_MEMORY_SCOPE_AGENT);
            if ((v & ~1u) == TAG_BASE) break;
            __builtin_amdgcn_s_sleep(1);
        }
        dirty |= (int)(v & 1u);
    }
    if (tid == 0) s_hit = 0;
    __syncthreads();
    if (dirty) atomicOr(&s_hit, 1);
    __syncthreads();
    dirty = s_hit;

    if (!dirty) {
        // ---- fast path: no pair anywhere within the loose gate ----
        float2 p = ((const float2*)pos)[i];
        float2 o = ((const float2*)ori)[i];
        float2 t = ((const float2*)tno)[i];
        out[2 * i]     = p.x + C_TV * o.x + t.x * ktr;   // translated, no moves
        out[2 * i + 1] = p.y + C_TV * o.y + t.y * ktr;
        // partials zero; osum = diagonal only
        epilogue4(p, o, del[i], rno[i], o.x, o.y, 0.f, 0.f, 0.f,
                  sumx, sumy, i, out);
        return;
    }

    // ---- dirty path (never taken on this input): block 0 recomputes ALL ----
    if (cb != 0) return;

    // translated positions into LDS
    for (int k = tid; k < NP; k += 256) {
        float2 p = ((const float2*)pos)[k];
        float2 o = ((const float2*)ori)[k];
        float2 t = ((const float2*)tno)[k];
        s_p[k] = make_float2(p.x + C_TV * o.x + t.x * ktr,
                             p.y + C_TV * o.y + t.y * ktr);
    }
    __syncthreads();

    // reference collision loop: step once, then while(had && c<1000)
    int prev_had = 1;
    for (int c = 0; c <= 1000 && prev_had; ++c) {
        int had = 0;
        for (int k = tid; k < NP; k += 256) {      // Jacobi moves from snapshot
            float2 q = s_p[k];
            float mx = 0.f, my = 0.f;
            for (int j = 0; j < NP; ++j) {
                float2 qj = s_p[j];
                float ex = qj.x - q.x;
                float ey = qj.y - q.y;
                float e2 = ex * ex + ey * ey;
                if (e2 <= COLL2_THR && j != k) {
                    float da = sqrtf(e2);
                    float safe = (da > 0.f) ? da : 1.f;
                    float ov = (OVC - da) * 0.5f;
                    mx += ex / safe * ov;
                    my += ey / safe * ov;
                    had = 1;
                }
            }
            wmv[k] = make_float2(mx, my);
        }
        if (tid == 0) s_hit = 0;
        __syncthreads();
        if (had) atomicOr(&s_hit, 1);
        __syncthreads();
        for (int k = tid; k < NP; k += 256) {      // apply
            float2 m = wmv[k];
            s_p[k] = make_float2(s_p[k].x - m.x, s_p[k].y - m.y);
        }
        __syncthreads();
        prev_had = s_hit;
    }

    for (int k = tid; k < NP; k += 256) {          // plane 0
        out[2 * k]     = s_p[k].x;
        out[2 * k + 1] = s_p[k].y;
    }
    __syncthreads();

    // neighbor scan on ORIGINAL positions
    for (int k = tid; k < NP; k += 256) s_p[k] = ((const float2*)pos)[k];
    __syncthreads();

    for (int k = tid; k < NP; k += 256) {
        float2 p = s_p[k];
        float2 o = ((const float2*)ori)[k];
        float angi = atan2f(o.y, o.x);
        float osx = 0.f, osy = 0.f, nr = 0.f, rrx = 0.f, rry = 0.f;
        for (int j = 0; j < NP; ++j) {
            float2 pj = s_p[j];
            float dx = pj.x - p.x;
            float dy = pj.y - p.y;
            float d2 = dx * dx + dy * dy;
            if (d2 <= RO2_THR && j != k) {
                float2 oj = ((const float2*)ori)[j];
                osx += oj.x; osy += oj.y;
                if (d2 <= RR2_THR) {
                    float ad = fabsf(angle_diff(angi, atan2f(oj.y, oj.x)));
                    if (ad < 0.5f * PI_F) {        // in_front
                        nr += 1.f; rrx += pj.x; rry += pj.y;
                    }
                }
            }
        }
        osx += o.x; osy += o.y;                    // ro diagonal
        epilogue4(p, o, del[k], rno[k], osx, osy, nr, rrx, rry,
                  sumx, sumy, k, out);
    }
}

extern "C" void kernel_launch(void* const* d_in, const int* in_sizes, int n_in,
                              void* d_out, int out_size, void* d_ws, size_t ws_size,
                              hipStream_t stream) {
    const float* pos = (const float*)d_in[0];
    const float* ori = (const float*)d_in[1];
    const float* del = (const float*)d_in[2];
    const float* rno = (const float*)d_in[3];
    const float* tno = (const float*)d_in[4];
    float* out = (float*)d_out;
    float* ws  = (float*)d_ws;

    fused<<<NBLK_TOT, 256, 0, stream>>>(pos, ori, del, rno, tno, out, ws);
}

// Round 7
// 12.280 us; speedup vs baseline: 1.2771x; 1.2771x over previous
//
#include <hip/hip_runtime.h>
#include <math.h>

#define NP 4096
#define JC 128           // j-chunk per detector block
#define NEP 16           // epilogue blocks (16 * 256 = 4096 particles)
#define NSCAN 272        // sum_{ib=0}^{15} 2*(ib+1)  (lower-triangle blocks)
#define PI_F 3.1415927410125732f

// thresholds (squared, monotone-equivalent to reference's abs() compares)
#define RR2_THR   (8e-06f * 8e-06f)                       // RR^2
#define RO2_THR   (2.815e-05f * 2.815e-05f)               // (RO+RC)^2
#define COLL2_THR (6.3e-06f * 6.3e-06f)                   // (2*RC)^2
#define OVC       (2.1f * 3.15e-06f)                      // 2.1*RC
#define EPS_F     1e-14f

#define C_TV   ((float)(0.2 * 5e-07))         // DT*VEL
#define C_ROT  ((float)(0.2 * 25.0 * 0.0028)) // DT*GAMMA*DR

// ws: int flags[NSCAN] (plain stores, rewritten every call), then
// float2 wmv[NP] scratch for the (never-taken) dirty path.
#define W_MV_OFF 1024    // float offset

__device__ __forceinline__ float angle_diff(float a, float b) {
    float diff = a - b;
    if (diff <= -PI_F) {
        float m = fmodf(diff, PI_F);     // python-mod semantics (divisor > 0)
        if (m < 0.f) m += PI_F;
        diff = m;
    }
    if (diff >= PI_F) diff -= 2.f * PI_F;
    return diff;
}

// epilogue planes 1..4 (new_ori, osum, left, right); caller writes plane 0.
// osx/osy must already include the ro-diagonal contribution.
__device__ __forceinline__ void epilogue4(
    float2 p, float2 o, float dlt, float rnoi,
    float osx, float osy, float nr, float rrx, float rry,
    float sumx, float sumy, int i, float* __restrict__ out)
{
    float ang = atan2f(o.y, o.x);

    float invn = 1.f / fmaxf(nr, 1.f);
    float sgn  = (nr > 0.f) ? 1.f : 0.f;
    float Sx = rrx * invn - p.x * sgn;
    float Sy = rry * invn - p.y * sgn;
    float ddx = -Sx, ddy = -Sy;

    float cmx = sumx * (1.f / 4096.f);
    float cmy = sumy * (1.f / 4096.f);
    float Px = cmx - p.x;
    float Py = cmy - p.y;

    float cd = cosf(dlt), sd = sinf(dlt);
    float lx = Px * cd - Py * sd, ly = Px * sd + Py * cd;   // Ps * e^{+i d}
    float rx = Px * cd + Py * sd, ry = Py * cd - Px * sd;   // Ps * e^{-i d}

    float la = sqrtf(lx * lx + ly * ly);
    float ra = sqrtf(rx * rx + ry * ry);
    float oa = sqrtf(osx * osx + osy * osy);
    float csl = (lx * osx + ly * osy) / (fmaxf(la, EPS_F) * fmaxf(oa, EPS_F));
    float csr = (rx * osx + ry * osy) / (fmaxf(ra, EPS_F) * fmaxf(oa, EPS_F));
    bool lc = (csl >= csr);
    float bx = lc ? lx : rx;
    float by = lc ? ly : ry;

    bool dnz = (ddx != 0.f) || (ddy != 0.f);
    float att;
    if (dnz) {
        att = angle_diff(atan2f(ddy, ddx), ang);
    } else {
        bool bnz = (bx != 0.f) || (by != 0.f);
        float ab = bnz ? atan2f(by, bx) : 0.f;   // angle(1) = 0
        att = angle_diff(ab, ang);
    }

    float s1r = sqrtf(2.0f * 0.0028f);   // sqrt(2*DR)
    float sdt = sqrtf(0.2f);             // sqrt(DT)
    float theta = C_ROT * sinf(att) + rnoi * s1r * sdt;
    float ct = cosf(theta), st = sinf(theta);
    float nox = o.x * ct - o.y * st;
    float noy = o.x * st + o.y * ct;

    out[2 * NP + 2 * i] = nox;  out[2 * NP + 2 * i + 1] = noy;
    out[4 * NP + 2 * i] = osx;  out[4 * NP + 2 * i + 1] = osy;
    out[6 * NP + 2 * i] = lx;   out[6 * NP + 2 * i + 1] = ly;
    out[8 * NP + 2 * i] = rx;   out[8 * NP + 2 * i + 1] = ry;
}

// ---------------- pass 1: fast-path epilogue (blocks 0..15, long pole first)
// + lower-triangle proximity detectors (blocks 16..287)
__global__ __launch_bounds__(256) void mainK(
    const float* __restrict__ pos, const float* __restrict__ ori,
    const float* __restrict__ del, const float* __restrict__ rno,
    const float* __restrict__ tno, float* __restrict__ out,
    float* __restrict__ ws)
{
    __shared__ float2 s_buf[256];    // epilogue: pos-sum tree; detector: j-stage
    __shared__ int s_hit;

    const int tid = threadIdx.x;
    const int b   = blockIdx.x;
    const float ktr = sqrtf(2.0f * 1.4e-14f) * sqrtf(0.2f);  // sqrt(2*DTRANS)*sqrt(DT)

    if (b < NEP) {
        // ---- fast-path epilogue: assumes no pair within the loose gate ----
        const int i = b * 256 + tid;

        // global position sum for cms (n_a == 4096 exactly; deterministic tree)
        float sx = 0.f, sy = 0.f;
        for (int k = tid; k < NP; k += 256) {
            float2 pk = ((const float2*)pos)[k];
            sx += pk.x; sy += pk.y;
        }
        s_buf[tid] = make_float2(sx, sy);
        __syncthreads();
        for (int s = 128; s > 0; s >>= 1) {
            if (tid < s) { s_buf[tid].x += s_buf[tid + s].x; s_buf[tid].y += s_buf[tid + s].y; }
            __syncthreads();
        }
        const float sumx = s_buf[0].x, sumy = s_buf[0].y;

        float2 p = ((const float2*)pos)[i];
        float2 o = ((const float2*)ori)[i];
        float2 t = ((const float2*)tno)[i];
        out[2 * i]     = p.x + C_TV * o.x + t.x * ktr;   // translated, no moves
        out[2 * i + 1] = p.y + C_TV * o.y + t.y * ktr;
        // partials zero; osum = ro diagonal only
        epilogue4(p, o, del[i], rno[i], o.x, o.y, 0.f, 0.f, 0.f,
                  sumx, sumy, i, out);
        return;
    }

    // ---- detector: any unordered pair (j<i) with d_orig <= RO2 gate? ----
    // Gate covers osum/rr (d<=2.815e-5) and collisions on translated points
    // (d_tr<=6.3e-6, |rel translation| <= ~1.1e-6 => d_orig <= 7.4e-6 << gate).
    const int s  = b - NEP;
    int ib = 0;                                  // base(ib) = ib*(ib+1)
    while ((ib + 1) * (ib + 2) <= s) ++ib;
    const int js = s - ib * (ib + 1);            // 0 .. 2*(ib+1)-1
    const int i  = ib * 256 + tid;
    const int jbase = js * JC;

    if (tid == 0) s_hit = 0;
    if (tid < JC) s_buf[tid] = ((const float2*)pos)[jbase + tid];
    __syncthreads();

    float2 pi = ((const float2*)pos)[i];
    bool hit = false;
    if (jbase + JC <= ib * 256) {                // slice fully below diagonal
        #pragma unroll 4
        for (int jj = 0; jj < JC; ++jj) {
            float2 pj = s_buf[jj];
            float dx = pj.x - pi.x;
            float dy = pj.y - pi.y;
            hit |= (dx * dx + dy * dy) <= RO2_THR;
        }
    } else {                                     // diagonal band: index check
        #pragma unroll 4
        for (int jj = 0; jj < JC; ++jj) {
            float2 pj = s_buf[jj];
            float dx = pj.x - pi.x;
            float dy = pj.y - pi.y;
            hit |= ((dx * dx + dy * dy) <= RO2_THR) && (jbase + jj < i);
        }
    }
    if (hit) atomicOr(&s_hit, 1);                // never taken in practice
    __syncthreads();
    if (tid == 0) ((int*)ws)[s] = s_hit;         // plain store; kernel boundary
}

// ---------------- pass 2: 1-block flag check; common case exits immediately.
// Dirty path: full faithful recompute from the raw inputs (never taken here).
__global__ __launch_bounds__(256) void checkK(
    const float* __restrict__ pos, const float* __restrict__ ori,
    const float* __restrict__ del, const float* __restrict__ rno,
    const float* __restrict__ tno, float* __restrict__ out,
    float* __restrict__ ws)
{
    __shared__ float2 s_p[NP];       // 32 KB (dirty path only)
    __shared__ float2 s_red[256];
    __shared__ int s_any;

    const int tid = threadIdx.x;
    const float ktr = sqrtf(2.0f * 1.4e-14f) * sqrtf(0.2f);

    if (tid == 0) s_any = 0;
    __syncthreads();
    int v = 0;
    if (tid < NSCAN / 4) {
        int4 f4 = ((const int4*)ws)[tid];
        v = f4.x | f4.y | f4.z | f4.w;
    }
    if (v) atomicOr(&s_any, 1);
    __syncthreads();
    if (!s_any) return;              // the always-taken path on this input

    // ================== dirty path: faithful full recompute ==================
    float2* wmv = (float2*)(ws + W_MV_OFF);

    // position sum for cms
    float sx = 0.f, sy = 0.f;
    for (int k = tid; k < NP; k += 256) {
        float2 pk = ((const float2*)pos)[k];
        sx += pk.x; sy += pk.y;
    }
    s_red[tid] = make_float2(sx, sy);
    __syncthreads();
    for (int s = 128; s > 0; s >>= 1) {
        if (tid < s) { s_red[tid].x += s_red[tid + s].x; s_red[tid].y += s_red[tid + s].y; }
        __syncthreads();
    }
    const float sumx = s_red[0].x, sumy = s_red[0].y;

    // translated positions into LDS
    for (int k = tid; k < NP; k += 256) {
        float2 p = ((const float2*)pos)[k];
        float2 o = ((const float2*)ori)[k];
        float2 t = ((const float2*)tno)[k];
        s_p[k] = make_float2(p.x + C_TV * o.x + t.x * ktr,
                             p.y + C_TV * o.y + t.y * ktr);
    }
    __syncthreads();
    if (tid == 0) s_any = 0;
    __syncthreads();

    // reference collision loop: step once, then while(had && iter<1000)
    int prev_had = 1;
    for (int c = 0; c <= 1000 && prev_had; ++c) {
        int had = 0;
        for (int k = tid; k < NP; k += 256) {      // Jacobi moves from snapshot
            float2 q = s_p[k];
            float mx = 0.f, my = 0.f;
            for (int j = 0; j < NP; ++j) {
                float2 qj = s_p[j];
                float ex = qj.x - q.x;
                float ey = qj.y - q.y;
                float e2 = ex * ex + ey * ey;
                if (e2 <= COLL2_THR && j != k) {
                    float da = sqrtf(e2);
                    float safe = (da > 0.f) ? da : 1.f;
                    float ov = (OVC - da) * 0.5f;
                    mx += ex / safe * ov;
                    my += ey / safe * ov;
                    had = 1;
                }
            }
            wmv[k] = make_float2(mx, my);
        }
        if (had) atomicOr(&s_any, 1);
        __syncthreads();                           // moves done, s_any final
        for (int k = tid; k < NP; k += 256) {
            float2 m = wmv[k];
            s_p[k] = make_float2(s_p[k].x - m.x, s_p[k].y - m.y);
        }
        prev_had = s_any;
        __syncthreads();                           // apply done, s_any read
        if (tid == 0) s_any = 0;
        __syncthreads();
    }

    for (int k = tid; k < NP; k += 256) {          // plane 0
        out[2 * k]     = s_p[k].x;
        out[2 * k + 1] = s_p[k].y;
    }
    __syncthreads();

    // neighbor scan on ORIGINAL positions
    for (int k = tid; k < NP; k += 256) s_p[k] = ((const float2*)pos)[k];
    __syncthreads();

    for (int k = tid; k < NP; k += 256) {
        float2 p = s_p[k];
        float2 o = ((const float2*)ori)[k];
        float angi = atan2f(o.y, o.x);
        float osx = 0.f, osy = 0.f, nr = 0.f, rrx = 0.f, rry = 0.f;
        for (int j = 0; j < NP; ++j) {
            float2 pj = s_p[j];
            float dx = pj.x - p.x;
            float dy = pj.y - p.y;
            float d2 = dx * dx + dy * dy;
            if (d2 <= RO2_THR && j != k) {
                float2 oj = ((const float2*)ori)[j];
                osx += oj.x; osy += oj.y;
                if (d2 <= RR2_THR) {
                    float ad = fabsf(angle_diff(angi, atan2f(oj.y, oj.x)));
                    if (ad < 0.5f * PI_F) {        // in_front
                        nr += 1.f; rrx += pj.x; rry += pj.y;
                    }
                }
            }
        }
        osx += o.x; osy += o.y;                    // ro diagonal
        epilogue4(p, o, del[k], rno[k], osx, osy, nr, rrx, rry,
                  sumx, sumy, k, out);
    }
}

extern "C" void kernel_launch(void* const* d_in, const int* in_sizes, int n_in,
                              void* d_out, int out_size, void* d_ws, size_t ws_size,
                              hipStream_t stream) {
    const float* pos = (const float*)d_in[0];
    const float* ori = (const float*)d_in[1];
    const float* del = (const float*)d_in[2];
    const float* rno = (const float*)d_in[3];
    const float* tno = (const float*)d_in[4];
    float* out = (float*)d_out;
    float* ws  = (float*)d_ws;

    mainK<<<NEP + NSCAN, 256, 0, stream>>>(pos, ori, del, rno, tno, out, ws);
    checkK<<<1, 256, 0, stream>>>(pos, ori, del, rno, tno, out, ws);
}